// Round 9
// baseline (130.980 us; speedup 1.0000x reference)
//
#include <hip/hip_runtime.h>

// SNN forward, two kernels. Round-9 = round-8 resubmitted verbatim (round 8
// hit an infra UnresponsiveContainer before running; source re-audited, no
// OOB / deadlock hazard found).
// Theory under test: per-instruction VMEM segment count. Every x-load
// instruction = ONE contiguous 1024 B span (64 lanes x 16 B, 64 B-aligned)
// vs R5's 4 discontiguous 256 B segments per instruction.
// Per pass a wave handles 4 consecutive rows (g-outer load order = near-
// linear 12.5 KB stream). W in LDS; W reads lane-linear 1024 B ds_read_b128
// (conflict-free), amortized over 4 rows.
// Tail (feats 768..783 = 4 f4/row): lanes with (ln&15)<4 load one f4
// (exec-masked; others contribute 0); W-tail address uses (ln&3) so it is
// always in-bounds; products routed to the owning row's accumulator via
// static cndmask-adds; the full 64-lane reduction sweeps them up.
// Reduction: 4 DPP butterflies + ds_swizzle xor16 + shfl xor32.

#define T_STEPS 64
#define BATCH   2048
#define FEAT    784
#define OUT_N   10
#define ROWS    (T_STEPS * BATCH)   // 131072

typedef __attribute__((ext_vector_type(4))) float f4;
typedef __attribute__((ext_vector_type(2))) float f2;

template <int CTRL>
__device__ __forceinline__ float dpp_mov(float v) {
    return __int_as_float(
        __builtin_amdgcn_update_dpp(0, __float_as_int(v), CTRL, 0xF, 0xF, true));
}
// sum within each aligned 16-lane group (verified bit-exact R4/R5)
__device__ __forceinline__ float red16(float v) {
    v += dpp_mov<0xB1>(v);    // xor 1
    v += dpp_mov<0x4E>(v);    // xor 2
    v += dpp_mov<0x141>(v);   // xor 7 (row_half_mirror)
    v += dpp_mov<0x140>(v);   // xor 15 (row_mirror)
    return v;
}
// full 64-lane sum, result replicated in all lanes
__device__ __forceinline__ float red64(float v) {
    v = red16(v);
    // xor 16 within each 32-lane group: BitMode offset = (16<<10)|0x1F
    v += __int_as_float(__builtin_amdgcn_ds_swizzle(__float_as_int(v), 0x401F));
    v += __shfl_xor(v, 32, 64);   // halves
    return v;
}

__global__ __launch_bounds__(256)
void snn_gemm(const float* __restrict__ x, const float* __restrict__ W,
              const float* __restrict__ bias, float* __restrict__ C) {
    __shared__ float Wl[OUT_N * FEAT];   // 31360 B

    {   // cooperative W load, vectorized
        const f4* Wg = (const f4*)W;
        f4* Ws = (f4*)Wl;
        for (int i = threadIdx.x; i < OUT_N * FEAT / 4; i += 256) Ws[i] = Wg[i];
    }
    __syncthreads();   // only barrier

    const int tid  = threadIdx.x;
    const int w    = tid >> 6;
    const int ln   = tid & 63;
    const int wgid = blockIdx.x * 4 + w;     // 0..8191, 16 rows each

    f2 bv[5];
#pragma unroll
    for (int p = 0; p < 5; ++p) { bv[p].x = bias[2 * p]; bv[p].y = bias[2 * p + 1]; }

    const int gsel = ln >> 4;    // row this lane's tail element belongs to
    const int tq   = ln & 15;    // tail quarter (valid when < 4)

#pragma unroll 1
    for (int p = 0; p < 4; ++p) {
        const long row0 = (long)wgid * 16 + p * 4;
        const float* xr0 = x + (size_t)row0 * FEAT;

        // ---- loads: per (g,c) one contiguous 1024 B span; g-outer = linear walk
        f4 xr[4][3];
#pragma unroll
        for (int g = 0; g < 4; ++g)
#pragma unroll
            for (int c = 0; c < 3; ++c)
                xr[g][c] = *(const f4*)(xr0 + (size_t)g * FEAT + c * 256 + ln * 4);
        // tail: 4 f4 per row, owned by lanes tq<4 (exec-masked load, else 0)
        f4 xt = {0.0f, 0.0f, 0.0f, 0.0f};
        if (tq < 4)
            xt = *(const f4*)(xr0 + (size_t)gsel * FEAT + 768 + tq * 4);

        float acc[4][OUT_N];
#pragma unroll
        for (int g = 0; g < 4; ++g)
#pragma unroll
            for (int o = 0; o < OUT_N; ++o) acc[g][o] = 0.0f;

        // ---- main FMA: W frag shared by the 4 rows (amortized)
#pragma unroll
        for (int c = 0; c < 3; ++c)
#pragma unroll
            for (int o = 0; o < OUT_N; ++o) {
                const f4 wf = *(const f4*)&Wl[o * FEAT + c * 256 + ln * 4];
#pragma unroll
                for (int g = 0; g < 4; ++g) {
                    acc[g][o] = fmaf(xr[g][c].x, wf.x, acc[g][o]);
                    acc[g][o] = fmaf(xr[g][c].y, wf.y, acc[g][o]);
                    acc[g][o] = fmaf(xr[g][c].z, wf.z, acc[g][o]);
                    acc[g][o] = fmaf(xr[g][c].w, wf.w, acc[g][o]);
                }
            }

        // ---- tail: per-lane dot (xt=0 for non-owner lanes), routed via cndmask
#pragma unroll
        for (int o = 0; o < OUT_N; ++o) {
            const f4 wt = *(const f4*)&Wl[o * FEAT + 768 + (ln & 3) * 4];  // in-bounds
            float s = xt.x * wt.x;
            s = fmaf(xt.y, wt.y, s);
            s = fmaf(xt.z, wt.z, s);
            s = fmaf(xt.w, wt.w, s);
            acc[0][o] += (gsel == 0) ? s : 0.0f;
            acc[1][o] += (gsel == 1) ? s : 0.0f;
            acc[2][o] += (gsel == 2) ? s : 0.0f;
            acc[3][o] += (gsel == 3) ? s : 0.0f;
        }

        // ---- full 64-lane reduction (each acc[g][o] summed across the wave)
#pragma unroll
        for (int g = 0; g < 4; ++g)
#pragma unroll
            for (int o = 0; o < OUT_N; ++o) acc[g][o] = red64(acc[g][o]);

        // ---- stores: 4 static exec-masked writer lanes, f2-packed + bias
#define STORE_ROW(G)                                                      \
        do {                                                              \
            float* Cr = C + (size_t)(row0 + (G)) * OUT_N;                 \
            _Pragma("unroll")                                             \
            for (int q = 0; q < 5; ++q) {                                 \
                f2 s;                                                     \
                s.x = acc[(G)][2 * q]     + bv[q].x;                      \
                s.y = acc[(G)][2 * q + 1] + bv[q].y;                      \
                *(f2*)&Cr[2 * q] = s;                                     \
            }                                                             \
        } while (0)
        if      (ln == 0) STORE_ROW(0);
        else if (ln == 1) STORE_ROW(1);
        else if (ln == 2) STORE_ROW(2);
        else if (ln == 3) STORE_ROW(3);
#undef STORE_ROW
    }
}

// Phase 2: one thread per (b, o); IF-neuron scan over t.
__global__ __launch_bounds__(256)
void snn_scan(const float* __restrict__ C, float* __restrict__ out) {
    const int idx = blockIdx.x * 256 + threadIdx.x;   // b*OUT_N + o
    if (idx >= BATCH * OUT_N) return;
    float v = 0.0f;
    float cnt = 0.0f;
#pragma unroll
    for (int t = 0; t < T_STEPS; ++t) {
        v += C[(size_t)t * BATCH * OUT_N + idx];
        if (v >= 1.0f) { cnt += 1.0f; v = 0.0f; }
    }
    out[idx] = cnt * (1.0f / 64.0f);
}

extern "C" void kernel_launch(void* const* d_in, const int* in_sizes, int n_in,
                              void* d_out, int out_size, void* d_ws, size_t ws_size,
                              hipStream_t stream) {
    const float* x    = (const float*)d_in[0];   // [64, 2048, 784] f32
    const float* W    = (const float*)d_in[1];   // [10, 784] f32
    const float* bias = (const float*)d_in[2];   // [10] f32
    float* out = (float*)d_out;                  // [2048, 10] f32
    float* C   = (float*)d_ws;                   // [131072, 10] f32 scratch

    snn_gemm<<<dim3(ROWS / 64), dim3(256), 0, stream>>>(x, W, bias, C);
    snn_scan<<<dim3((BATCH * OUT_N + 255) / 256), dim3(256), 0, stream>>>(C, out);
}

// Round 11
// 89.666 us; speedup vs baseline: 1.4608x; 1.4608x over previous
//
#include <hip/hip_runtime.h>

// SNN forward, two kernels. Round-11 = round-10 resubmitted verbatim (round
// 10 hit an infra UnresponsiveContainer before running; source re-audited:
// all loads in-bounds, no barrier/waitcnt hazards).
// Clean A/B vs R5 (88.3 us) testing ONE variable: per-VMEM-instruction
// segment shape.
//   R5 : wave = 4 row-slots x 16 f-lanes -> each x-load = 4 x 256 B segments
//   now: wave = 2 row-slots x 32 f-lanes -> each x-load = 2 x 512 B segments
// Everything else structurally identical: depth-1 chunk prefetch (unroll 2),
// same FMA count per chunk, W in LDS with multi-slot broadcast b128 reads,
// DPP reduction (+ exactly one ds_swizzle xor16 per value, validated bit-
// exact in R9), f2-packed stores by one writer lane per 32-group, bias in
// registers. Block = 32 rows (4 waves x 8), grid = 4096.

#define T_STEPS 64
#define BATCH   2048
#define FEAT    784
#define OUT_N   10
#define ROWS    (T_STEPS * BATCH)   // 131072

typedef __attribute__((ext_vector_type(4))) float f4;
typedef __attribute__((ext_vector_type(2))) float f2;

template <int CTRL>
__device__ __forceinline__ float dpp_mov(float v) {
    return __int_as_float(
        __builtin_amdgcn_update_dpp(0, __float_as_int(v), CTRL, 0xF, 0xF, true));
}
// sum within each aligned 16-lane group (bit-exact validated R4/R5/R9)
__device__ __forceinline__ float red16(float v) {
    v += dpp_mov<0xB1>(v);    // xor 1
    v += dpp_mov<0x4E>(v);    // xor 2
    v += dpp_mov<0x141>(v);   // xor 7 (row_half_mirror)
    v += dpp_mov<0x140>(v);   // xor 15 (row_mirror)
    return v;
}
// sum within each aligned 32-lane group (swizzle xor16 validated in R9)
__device__ __forceinline__ float red32(float v) {
    v = red16(v);
    v += __int_as_float(__builtin_amdgcn_ds_swizzle(__float_as_int(v), 0x401F));
    return v;
}

__global__ __launch_bounds__(256)
void snn_gemm(const float* __restrict__ x, const float* __restrict__ W,
              const float* __restrict__ bias, float* __restrict__ C) {
    __shared__ float Wl[OUT_N * FEAT];   // 31360 B

    {   // cooperative W load, vectorized
        const f4* Wg = (const f4*)W;
        f4* Ws = (f4*)Wl;
        for (int i = threadIdx.x; i < OUT_N * FEAT / 4; i += 256) Ws[i] = Wg[i];
    }
    __syncthreads();   // only barrier

    const int tid = threadIdx.x;
    const int w   = tid >> 6;
    const int ln  = tid & 63;
    const int l32 = ln & 31;         // feature slice (32 lanes)
    const int r   = ln >> 5;         // row slot (2 slots)
    const long row0 = (long)blockIdx.x * 32 + w * 8 + r * 4;

    const float* xbase = x + (size_t)row0 * FEAT + 4 * l32;

    f2 bv[5];
#pragma unroll
    for (int p = 0; p < 5; ++p) { bv[p].x = bias[2 * p]; bv[p].y = bias[2 * p + 1]; }

    float acc[4][OUT_N];
#pragma unroll
    for (int g = 0; g < 4; ++g)
#pragma unroll
        for (int o = 0; o < OUT_N; ++o) acc[g][o] = 0.0f;

    // prefetch chunk 0 (chunk = 128 floats; 6 chunks cover feats 0..767)
    f4 cur[4];
#pragma unroll
    for (int g = 0; g < 4; ++g)
        cur[g] = *(const f4*)(xbase + (size_t)g * FEAT);

#pragma unroll 2
    for (int c = 0; c < 6; ++c) {
        f4 nxt[4];
        if (c < 5) {
#pragma unroll
            for (int g = 0; g < 4; ++g)
                nxt[g] = *(const f4*)(xbase + (size_t)g * FEAT + (c + 1) * 128);
        }
#pragma unroll
        for (int o = 0; o < OUT_N; ++o) {
            const f4 wf = *(const f4*)&Wl[o * FEAT + c * 128 + l32 * 4];
#pragma unroll
            for (int g = 0; g < 4; ++g) {
                acc[g][o] = fmaf(cur[g].x, wf.x, acc[g][o]);
                acc[g][o] = fmaf(cur[g].y, wf.y, acc[g][o]);
                acc[g][o] = fmaf(cur[g].z, wf.z, acc[g][o]);
                acc[g][o] = fmaf(cur[g].w, wf.w, acc[g][o]);
            }
        }
        if (c < 5) {
#pragma unroll
            for (int g = 0; g < 4; ++g) cur[g] = nxt[g];
        }
    }

    // tail feats 768..783: lanes l32 < 4 add 4 floats each
    if (l32 < 4) {
#pragma unroll
        for (int g = 0; g < 4; ++g) {
            const f4 xt = *(const f4*)(xbase + (size_t)g * FEAT + 768);
#pragma unroll
            for (int o = 0; o < OUT_N; ++o) {
                const f4 wf = *(const f4*)&Wl[o * FEAT + 768 + l32 * 4];
                acc[g][o] = fmaf(xt.x, wf.x, acc[g][o]);
                acc[g][o] = fmaf(xt.y, wf.y, acc[g][o]);
                acc[g][o] = fmaf(xt.z, wf.z, acc[g][o]);
                acc[g][o] = fmaf(xt.w, wf.w, acc[g][o]);
            }
        }
    }

    // reduce over the 32 f-lanes (4 DPP + 1 ds_swizzle per value)
#pragma unroll
    for (int g = 0; g < 4; ++g)
#pragma unroll
        for (int o = 0; o < OUT_N; ++o) acc[g][o] = red32(acc[g][o]);

    if (l32 == 0) {   // lanes 0 and 32: one writer per 32-group
#pragma unroll
        for (int g = 0; g < 4; ++g) {
            float* Cr = C + (size_t)(row0 + g) * OUT_N;   // 40 B stride, 8-aligned
#pragma unroll
            for (int q = 0; q < 5; ++q) {
                f2 s;
                s.x = acc[g][2 * q]     + bv[q].x;
                s.y = acc[g][2 * q + 1] + bv[q].y;
                *(f2*)&Cr[2 * q] = s;
            }
        }
    }
}

// Phase 2: one thread per (b, o); IF-neuron scan over t.
__global__ __launch_bounds__(256)
void snn_scan(const float* __restrict__ C, float* __restrict__ out) {
    const int idx = blockIdx.x * 256 + threadIdx.x;   // b*OUT_N + o
    if (idx >= BATCH * OUT_N) return;
    float v = 0.0f;
    float cnt = 0.0f;
#pragma unroll
    for (int t = 0; t < T_STEPS; ++t) {
        v += C[(size_t)t * BATCH * OUT_N + idx];
        if (v >= 1.0f) { cnt += 1.0f; v = 0.0f; }
    }
    out[idx] = cnt * (1.0f / 64.0f);
}

extern "C" void kernel_launch(void* const* d_in, const int* in_sizes, int n_in,
                              void* d_out, int out_size, void* d_ws, size_t ws_size,
                              hipStream_t stream) {
    const float* x    = (const float*)d_in[0];   // [64, 2048, 784] f32
    const float* W    = (const float*)d_in[1];   // [10, 784] f32
    const float* bias = (const float*)d_in[2];   // [10] f32
    float* out = (float*)d_out;                  // [2048, 10] f32
    float* C   = (float*)d_ws;                   // [131072, 10] f32 scratch

    snn_gemm<<<dim3(ROWS / 32), dim3(256), 0, stream>>>(x, W, bias, C);
    snn_scan<<<dim3((BATCH * OUT_N + 255) / 256), dim3(256), 0, stream>>>(C, out);
}

// Round 12
// 89.284 us; speedup vs baseline: 1.4670x; 1.0043x over previous
//
#include <hip/hip_runtime.h>

// SNN forward, two kernels. Round-12 = R5 structure (best, 88.3 us) + ONE new
// variable: NON-TEMPORAL memory hints on the read-once / write-once streams.
//   - x loads (411 MB, read exactly once): __builtin_nontemporal_load ->
//     nt/sc cache bits, skip L1/L2/LLC allocation+eviction work.
//   - C stores in gemm and C reads in scan (write-once/read-once round trip).
//   - scan t-loop fully unrolled so its 64 dependent 4B loads issue together.
// Everything else identical to R5: wave = 4 row-slots x 16 f-lanes, 4 rows
// per lane-slot, depth-1 chunk prefetch (unroll 2), W in LDS broadcast b128,
// DPP-only 16-lane reduction, f2-packed stores, bias in registers.

#define T_STEPS 64
#define BATCH   2048
#define FEAT    784
#define OUT_N   10
#define ROWS    (T_STEPS * BATCH)   // 131072

typedef __attribute__((ext_vector_type(4))) float f4;
typedef __attribute__((ext_vector_type(2))) float f2;

template <int CTRL>
__device__ __forceinline__ float dpp_mov(float v) {
    return __int_as_float(
        __builtin_amdgcn_update_dpp(0, __float_as_int(v), CTRL, 0xF, 0xF, true));
}
// sum within each aligned 16-lane group (bit-exact validated R4/R5/R9/R11)
__device__ __forceinline__ float red16(float v) {
    v += dpp_mov<0xB1>(v);    // xor 1
    v += dpp_mov<0x4E>(v);    // xor 2
    v += dpp_mov<0x141>(v);   // xor 7 (row_half_mirror)
    v += dpp_mov<0x140>(v);   // xor 15 (row_mirror)
    return v;
}

__global__ __launch_bounds__(256)
void snn_gemm(const float* __restrict__ x, const float* __restrict__ W,
              const float* __restrict__ bias, float* __restrict__ C) {
    __shared__ float Wl[OUT_N * FEAT];   // 31360 B

    {   // cooperative W load, vectorized (W is reused -> normal cached loads)
        const f4* Wg = (const f4*)W;
        f4* Ws = (f4*)Wl;
        for (int i = threadIdx.x; i < OUT_N * FEAT / 4; i += 256) Ws[i] = Wg[i];
    }
    __syncthreads();   // only barrier

    const int tid  = threadIdx.x;
    const int w    = tid >> 6;
    const int ln   = tid & 63;
    const int l16  = ln & 15;        // feature slice
    const int r    = ln >> 4;        // row slot
    const long row0 = (long)blockIdx.x * 64 + w * 16 + r * 4;

    const float* xbase = x + (size_t)row0 * FEAT + 4 * l16;

    f2 bv[5];
#pragma unroll
    for (int p = 0; p < 5; ++p) { bv[p].x = bias[2 * p]; bv[p].y = bias[2 * p + 1]; }

    float acc[4][OUT_N];
#pragma unroll
    for (int g = 0; g < 4; ++g)
#pragma unroll
        for (int o = 0; o < OUT_N; ++o) acc[g][o] = 0.0f;

    // prefetch chunk 0 (nontemporal: read-once stream)
    f4 cur[4];
#pragma unroll
    for (int g = 0; g < 4; ++g)
        cur[g] = __builtin_nontemporal_load((const f4*)(xbase + (size_t)g * FEAT));

#pragma unroll 2
    for (int c = 0; c < 12; ++c) {
        f4 nxt[4];
        if (c < 11) {
#pragma unroll
            for (int g = 0; g < 4; ++g)
                nxt[g] = __builtin_nontemporal_load(
                    (const f4*)(xbase + (size_t)g * FEAT + (c + 1) * 64));
        }
#pragma unroll
        for (int o = 0; o < OUT_N; ++o) {
            const f4 wf = *(const f4*)&Wl[o * FEAT + c * 64 + l16 * 4];
#pragma unroll
            for (int g = 0; g < 4; ++g) {
                acc[g][o] = fmaf(cur[g].x, wf.x, acc[g][o]);
                acc[g][o] = fmaf(cur[g].y, wf.y, acc[g][o]);
                acc[g][o] = fmaf(cur[g].z, wf.z, acc[g][o]);
                acc[g][o] = fmaf(cur[g].w, wf.w, acc[g][o]);
            }
        }
        if (c < 11) {
#pragma unroll
            for (int g = 0; g < 4; ++g) cur[g] = nxt[g];
        }
    }

    // tail feats 768..783: lanes l16 < 4 add 4 floats each
    if (l16 < 4) {
#pragma unroll
        for (int g = 0; g < 4; ++g) {
            const f4 xt = __builtin_nontemporal_load(
                (const f4*)(xbase + (size_t)g * FEAT + 768));
#pragma unroll
            for (int o = 0; o < OUT_N; ++o) {
                const f4 wf = *(const f4*)&Wl[o * FEAT + 768 + l16 * 4];
                acc[g][o] = fmaf(xt.x, wf.x, acc[g][o]);
                acc[g][o] = fmaf(xt.y, wf.y, acc[g][o]);
                acc[g][o] = fmaf(xt.z, wf.z, acc[g][o]);
                acc[g][o] = fmaf(xt.w, wf.w, acc[g][o]);
            }
        }
    }

    // reduce over the 16 f-lanes on the VALU pipe (DPP butterflies)
#pragma unroll
    for (int g = 0; g < 4; ++g)
#pragma unroll
        for (int o = 0; o < OUT_N; ++o) acc[g][o] = red16(acc[g][o]);

    if (l16 == 0) {
#pragma unroll
        for (int g = 0; g < 4; ++g) {
            float* Cr = C + (size_t)(row0 + g) * OUT_N;   // 40 B stride, 8-aligned
#pragma unroll
            for (int q = 0; q < 5; ++q) {
                f2 s;
                s.x = acc[g][2 * q]     + bv[q].x;
                s.y = acc[g][2 * q + 1] + bv[q].y;
                __builtin_nontemporal_store(s, (f2*)&Cr[2 * q]);
            }
        }
    }
}

// Phase 2: one thread per (b, o); IF-neuron scan over t. Fully unrolled so
// all 64 strided loads are issued up front (read-once: nontemporal).
__global__ __launch_bounds__(256)
void snn_scan(const float* __restrict__ C, float* __restrict__ out) {
    const int idx = blockIdx.x * 256 + threadIdx.x;   // b*OUT_N + o
    if (idx >= BATCH * OUT_N) return;
    float c[T_STEPS];
#pragma unroll
    for (int t = 0; t < T_STEPS; ++t)
        c[t] = __builtin_nontemporal_load(&C[(size_t)t * BATCH * OUT_N + idx]);
    float v = 0.0f;
    float cnt = 0.0f;
#pragma unroll
    for (int t = 0; t < T_STEPS; ++t) {
        v += c[t];
        if (v >= 1.0f) { cnt += 1.0f; v = 0.0f; }
    }
    out[idx] = cnt * (1.0f / 64.0f);
}

extern "C" void kernel_launch(void* const* d_in, const int* in_sizes, int n_in,
                              void* d_out, int out_size, void* d_ws, size_t ws_size,
                              hipStream_t stream) {
    const float* x    = (const float*)d_in[0];   // [64, 2048, 784] f32
    const float* W    = (const float*)d_in[1];   // [10, 784] f32
    const float* bias = (const float*)d_in[2];   // [10] f32
    float* out = (float*)d_out;                  // [2048, 10] f32
    float* C   = (float*)d_ws;                   // [131072, 10] f32 scratch

    snn_gemm<<<dim3(ROWS / 64), dim3(256), 0, stream>>>(x, W, bias, C);
    snn_scan<<<dim3((BATCH * OUT_N + 255) / 256), dim3(256), 0, stream>>>(C, out);
}

// Round 13
// 87.764 us; speedup vs baseline: 1.4924x; 1.0173x over previous
//
#include <hip/hip_runtime.h>

// SNN forward, ONE fused kernel. Round-13 = R5's proven load/FMA/reduce
// structure (best two-kernel: 88.3 us) with the IF-scan fused in, removing:
//   - the 2nd launch (~4 us serialized),
//   - the 80-block latency-dominated scan kernel (~3-5 us),
//   - the 10.5 MB C round-trip.
// Remap: block = one batch column b (2048 blocks); wave w covers t-rows
// {w*16 + r*4 + g}, physical row = t*2048 + b. Per-instruction access shape
// is IDENTICAL to R5 (4 x 256 B segments; shape proven irrelevant in R11) --
// only inter-segment distance changes. Epilogue: c[t][o] -> LDS part
// [64][10], one __syncthreads, lanes 0..9 run the sequential 64-step IF scan
// in LDS and store out[b][o]. No workspace use.

#define T_STEPS 64
#define BATCH   2048
#define FEAT    784
#define OUT_N   10

typedef __attribute__((ext_vector_type(4))) float f4;
typedef __attribute__((ext_vector_type(2))) float f2;

template <int CTRL>
__device__ __forceinline__ float dpp_mov(float v) {
    return __int_as_float(
        __builtin_amdgcn_update_dpp(0, __float_as_int(v), CTRL, 0xF, 0xF, true));
}
// sum within each aligned 16-lane group (bit-exact validated R4/R5/R9/R11/R12)
__device__ __forceinline__ float red16(float v) {
    v += dpp_mov<0xB1>(v);    // xor 1
    v += dpp_mov<0x4E>(v);    // xor 2
    v += dpp_mov<0x141>(v);   // xor 7 (row_half_mirror)
    v += dpp_mov<0x140>(v);   // xor 15 (row_mirror)
    return v;
}

__global__ __launch_bounds__(256)
void snn_fused(const float* __restrict__ x, const float* __restrict__ W,
               const float* __restrict__ bias, float* __restrict__ out) {
    __shared__ float Wl[OUT_N * FEAT];       // 31360 B
    __shared__ float part[T_STEPS * OUT_N];  // 2560 B: c[t][o]

    {   // cooperative W load, vectorized
        const f4* Wg = (const f4*)W;
        f4* Ws = (f4*)Wl;
        for (int i = threadIdx.x; i < OUT_N * FEAT / 4; i += 256) Ws[i] = Wg[i];
    }
    __syncthreads();

    const int tid = threadIdx.x;
    const int w   = tid >> 6;
    const int ln  = tid & 63;
    const int l16 = ln & 15;         // feature slice
    const int r   = ln >> 4;         // row slot
    const int b   = blockIdx.x;
    const int t0  = w * 16 + r * 4;  // first t-row of this slot

    // physical row of t = t*BATCH + b; g-stride = BATCH*FEAT floats
    const float* xbase = x + ((size_t)t0 * BATCH + b) * FEAT + 4 * l16;
    const size_t gstr  = (size_t)BATCH * FEAT;

    float acc[4][OUT_N];
#pragma unroll
    for (int g = 0; g < 4; ++g)
#pragma unroll
        for (int o = 0; o < OUT_N; ++o) acc[g][o] = 0.0f;

    // prefetch chunk 0
    f4 cur[4];
#pragma unroll
    for (int g = 0; g < 4; ++g)
        cur[g] = *(const f4*)(xbase + gstr * g);

#pragma unroll 2
    for (int c = 0; c < 12; ++c) {
        f4 nxt[4];
        if (c < 11) {
#pragma unroll
            for (int g = 0; g < 4; ++g)
                nxt[g] = *(const f4*)(xbase + gstr * g + (c + 1) * 64);
        }
#pragma unroll
        for (int o = 0; o < OUT_N; ++o) {
            const f4 wf = *(const f4*)&Wl[o * FEAT + c * 64 + l16 * 4];
#pragma unroll
            for (int g = 0; g < 4; ++g) {
                acc[g][o] = fmaf(cur[g].x, wf.x, acc[g][o]);
                acc[g][o] = fmaf(cur[g].y, wf.y, acc[g][o]);
                acc[g][o] = fmaf(cur[g].z, wf.z, acc[g][o]);
                acc[g][o] = fmaf(cur[g].w, wf.w, acc[g][o]);
            }
        }
        if (c < 11) {
#pragma unroll
            for (int g = 0; g < 4; ++g) cur[g] = nxt[g];
        }
    }

    // tail feats 768..783: lanes l16 < 4 add 4 floats each
    if (l16 < 4) {
#pragma unroll
        for (int g = 0; g < 4; ++g) {
            const f4 xt = *(const f4*)(xbase + gstr * g + 768);
#pragma unroll
            for (int o = 0; o < OUT_N; ++o) {
                const f4 wf = *(const f4*)&Wl[o * FEAT + 768 + l16 * 4];
                acc[g][o] = fmaf(xt.x, wf.x, acc[g][o]);
                acc[g][o] = fmaf(xt.y, wf.y, acc[g][o]);
                acc[g][o] = fmaf(xt.z, wf.z, acc[g][o]);
                acc[g][o] = fmaf(xt.w, wf.w, acc[g][o]);
            }
        }
    }

    // reduce over the 16 f-lanes (DPP butterflies, VALU pipe)
#pragma unroll
    for (int g = 0; g < 4; ++g)
#pragma unroll
        for (int o = 0; o < OUT_N; ++o) acc[g][o] = red16(acc[g][o]);

    // c[t][o] -> LDS (16 writer lanes per wave; f2-packed, 40 B row stride)
    if (l16 == 0) {
#pragma unroll
        for (int g = 0; g < 4; ++g) {
            float* p = &part[(t0 + g) * OUT_N];
#pragma unroll
            for (int q = 0; q < 5; ++q) {
                f2 s;
                s.x = acc[g][2 * q];
                s.y = acc[g][2 * q + 1];
                *(f2*)&p[2 * q] = s;
            }
        }
    }
    __syncthreads();   // end-of-kernel barrier: drain is harmless here

    // sequential IF scan over t, one lane per output unit
    if (tid < OUT_N) {
        const float bo = bias[tid];
        float v = 0.0f, cnt = 0.0f;
#pragma unroll
        for (int t = 0; t < T_STEPS; ++t) {
            const float vv = v + part[t * OUT_N + tid] + bo;
            const bool  s  = (vv >= 1.0f);
            cnt += s ? 1.0f : 0.0f;
            v = s ? 0.0f : vv;
        }
        out[b * OUT_N + tid] = cnt * (1.0f / 64.0f);
    }
}

extern "C" void kernel_launch(void* const* d_in, const int* in_sizes, int n_in,
                              void* d_out, int out_size, void* d_ws, size_t ws_size,
                              hipStream_t stream) {
    const float* x    = (const float*)d_in[0];   // [64, 2048, 784] f32
    const float* W    = (const float*)d_in[1];   // [10, 784] f32
    const float* bias = (const float*)d_in[2];   // [10] f32
    float* out = (float*)d_out;                  // [2048, 10] f32

    snn_fused<<<dim3(BATCH), dim3(256), 0, stream>>>(x, W, bias, out);
}